// Round 1
// 891.442 us; speedup vs baseline: 1.0006x; 1.0006x over previous
//
#include <hip/hip_runtime.h>
#include <stdint.h>
#include <math.h>

// EncoderSRNN: T=127 steps, BSZ=32 items, HDIM=256, SDIM=128, SSZ=128.
// One WG (1024 threads = 16 waves) per item. v2: 3 barriers/step (was 5):
//  - B2 removed: Phase B h2s computes hid inline from staggered f32 accih/acchp;
//    softmax on wave 0 (Wh2i staged in LDS); hid finalize on waves 1-2.
//  - S_e removed: stack stays in LDS single-buffered (own rows are same-thread),
//    cross-wave boundary rows go through double-buffered halo arrays.
//  - e2h pair-interleaved layout: window term = 4x ds_read_b128 (was 8x b64).
//  - prep fused into one kernel (e2h reads f32 We2h directly).

#define T_STEPS 127

// flat f32 output offsets (outputs, hid, stack, acts, top_elems)
#define OUT_OFF   0
#define HID_OFF   1040384
#define STACK_OFF 1048576
#define ACTS_OFF  1572864
#define TE_OFF    1580992

// ws layout (uint4 granularity for weight blobs):
//  uint4 [0,16384):      W1 = s2h (tid<512) / h2h (tid>=512), per-thread 16 uint4
//  uint4 [16384,20480):  W3 = h2s, K-split-8 layout, per-thread 8 uint4
//  uint4 [20480,24576):  W2 = s2u, K-split-8 layout, per-thread 8 uint4
//  uint  [131072,393216): E2H f16-pairs per item: [b][r2*256+j] = (row2r2,row2r2+1)
#define W3_OFF 16384
#define W2_OFF 20480
#define E2H_OFF_U 131072

typedef _Float16 h2 __attribute__((ext_vector_type(2)));

__device__ __forceinline__ unsigned packh2(float a, float b){
  h2 v; v.x = (_Float16)a; v.y = (_Float16)b;
  return __builtin_bit_cast(unsigned, v);
}
__device__ __forceinline__ float h2loF(unsigned u){ h2 v = __builtin_bit_cast(h2,u); return (float)v.x; }
__device__ __forceinline__ float h2hiF(unsigned u){ h2 v = __builtin_bit_cast(h2,u); return (float)v.y; }

#if __has_builtin(__builtin_amdgcn_fdot2)
__device__ __forceinline__ float fdot2(unsigned a, unsigned b, float c){
  return __builtin_amdgcn_fdot2(__builtin_bit_cast(h2,a), __builtin_bit_cast(h2,b), c, false);
}
#else
__device__ __forceinline__ float fdot2(unsigned a, unsigned b, float c){
  return c + h2loF(a)*h2loF(b) + h2hiF(a)*h2hiF(b);
}
#endif

// chunked (bank-staggered) layout for packed act vectors: logical uint u ->
// physical 12*(u>>3) + (u&7).  16 chunks x 12 uints = 192 uints.
#define CHOFF(u) (12*((u)>>3) + ((u)&7))
// staggered f32 layout for acc arrays: logical float f -> 20*(f>>4) + (f&15).
// STGP maps PAIR index p (f=2p): 16 chunks x 20 words = 320 floats.
#define STGP(p)  (20*((p)>>3) + 2*((p)&7))

// ---------------- fused prep: pack weights + E2H ----------------
// blocks [0,256): E2H = emb @ We2h^T (f32 weights), f16 row-pairs
// blocks [256,352): pack W1/W3/W2 f16 blobs
__global__ void prep_all(const int* __restrict__ inputs, const float* __restrict__ embW,
                         const float* __restrict__ We2h,
                         const float* __restrict__ Ws2h, const float* __restrict__ Wh2h,
                         const float* __restrict__ Wh2s, const float* __restrict__ Ws2u,
                         uint4* __restrict__ out4, unsigned* __restrict__ e2hpk){
  int tid = threadIdx.x;
  int bi  = blockIdx.x;
  if (bi >= 256){
    int gid = (bi-256)*256 + tid;              // [0, 24576)
    const float* src;
    if (gid < 16384){                          // W1: i in [0,16), t in [0,1024)
      int i = gid >> 10, t_ = gid & 1023;
      const float* S = (t_ < 512) ? Ws2h : Wh2h;
      int r = t_ & 511, jp = r >> 2, ks = r & 3;
      int j  = 2*jp + (i >> 3);
      int k0 = ks*64 + (i & 7)*8;
      src = S + j*256 + k0;
    } else {                                   // W3 / W2, K-split-8 layout
      int l = gid - 16384;
      int region = l >> 12, li = l & 4095;     // 0: h2s, 1: s2u
      int i = li >> 9, rB = li & 511;
      int jp = rB >> 3, ks = rB & 7;
      int j  = 2*jp + (i >> 2);
      int k0 = ks*32 + (i & 3)*8;
      src = (region ? Ws2u : Wh2s) + j*256 + k0;
    }
    uint4 r4;
    r4.x = packh2(src[0], src[1]); r4.y = packh2(src[2], src[3]);
    r4.z = packh2(src[4], src[5]); r4.w = packh2(src[6], src[7]);
    out4[gid] = r4;
    return;
  }
  // ---- E2H part ----
  __shared__ float emb[8][256];
  int r2 = bi >> 3, bg = bi & 7;
  for (int q=0;q<8;q++){
    int rr = q >> 2, bb = q & 3;
    int tok = inputs[(2*r2+rr)*32 + bg*4+bb];
    emb[q][tid] = embW[tok*256 + tid];
  }
  __syncthreads();
  float acc[8] = {0.f,0.f,0.f,0.f,0.f,0.f,0.f,0.f};
  for (int i8=0;i8<32;i8++){
    float4 f0 = *(const float4*)&We2h[tid*256 + i8*8];
    float4 f1 = *(const float4*)&We2h[tid*256 + i8*8 + 4];
    float wv[8] = {f0.x,f0.y,f0.z,f0.w,f1.x,f1.y,f1.z,f1.w};
    #pragma unroll
    for (int c=0;c<4;c++){
      float lo = wv[2*c], hi = wv[2*c+1];
      int k = i8*8 + c*2;
      #pragma unroll
      for (int q=0;q<8;q++)
        acc[q] += emb[q][k]*lo + emb[q][k+1]*hi;
    }
  }
  int base = (bg*4)*8192 + r2*256 + tid;
  #pragma unroll
  for (int bb=0;bb<4;bb++)
    e2hpk[base + bb*8192] = packh2(acc[bb], acc[4+bb]);  // (row 2r2, row 2r2+1)
}

// ---------------- main sequential kernel ----------------
__global__ __attribute__((amdgpu_flat_work_group_size(1024,1024), amdgpu_waves_per_eu(4,4)))
void srnn_main(const uint4* __restrict__ ws4, const unsigned* __restrict__ wsu,
               const float* __restrict__ b_e2h, const float* __restrict__ b_s2h,
               const float* __restrict__ b_h2h, const float* __restrict__ Wh2i,
               const float* __restrict__ b_h2i, const float* __restrict__ b_h2s,
               const float* __restrict__ b_s2u, const float* __restrict__ empty_el,
               float* __restrict__ out)
{
  __shared__ __align__(16) float    stk_s[128*128];     // stack f32, 64 KB
  __shared__ __align__(16) unsigned e2h4[16*520];       // pair-interleaved e2h
  __shared__ __align__(16) float    halo_top[2][16*128];// row0 of each group, dbuf
  __shared__ __align__(16) float    halo_bot[2][16*128];// row7 of each group, dbuf
  __shared__ __align__(16) float    accih_st[320], acchp_st[320]; // staggered f32
  __shared__ __align__(16) unsigned s_pk[192], hid_pk[192];       // f16, chunked
  __shared__ __align__(16) float    pv_s[128], uv_s[128];
  __shared__ __align__(16) float    whi_s[768];         // Wh2i rows 0..2
  __shared__ float    wbuf[2][192];
  __shared__ unsigned pkwc[32];
  __shared__ float    pp_s, pq_s;

  const int tid = threadIdx.x;
  const int b   = blockIdx.x;
  const int aside = tid >> 9;           // phase A: 0=ih(s2h+window), 1=hp(h2h)
  const int ar  = tid & 511;
  const int ajp = ar >> 2;              // output pair 0..127
  const int aks = ar & 3;               // K-split 4 (K=64 each)
  const int rB  = tid & 511;
  const int jpB = rB >> 3;              // phase B output pair 0..63
  const int ksB = rB & 7;               // phase B K-split 8 (K=32 each)
  const int h2sSide = (tid >= 512);     // B: waves 8-15 h2s (heavy), 0-7 s2u
  const int g   = tid >> 6;             // stack: wave id = row-group (8 rows)
  const int cp  = tid & 63;             // stack: column pair

  // ---- preload weights into registers (24 uint4 = 96 regs, same as before) ----
  uint4 w1r[16], wBr[8];
  #pragma unroll
  for (int i=0;i<16;i++) w1r[i] = ws4[i*1024 + tid];
  {
    int wbase = h2sSide ? W3_OFF : W2_OFF;
    #pragma unroll
    for (int i=0;i<8;i++) wBr[i] = ws4[wbase + i*512 + rB];
  }

  float bA0=0.f, bA1=0.f;
  if (aks==0){
    int j0 = 2*ajp;
    if (aside==0){ bA0 = b_e2h[j0]+b_s2h[j0]; bA1 = b_e2h[j0+1]+b_s2h[j0+1]; }
    else         { bA0 = b_h2h[j0];           bA1 = b_h2h[j0+1]; }
  }
  float bB0=0.f, bB1=0.f;
  if (ksB==0){
    const float* bb = h2sSide ? b_h2s : b_s2u;
    bB0 = bb[2*jpB]; bB1 = bb[2*jpB+1];
  }
  const float bi0=b_h2i[0], bi1=b_h2i[1], bi2=b_h2i[2];

  // ---- init LDS state ----
  const unsigned* e2hg = wsu + E2H_OFF_U + b*8192;
  #pragma unroll
  for (int q=0;q<8;q++){
    int idx = q*1024 + tid;
    int r2 = idx >> 8, j = idx & 255;
    e2h4[(r2>>1)*520 + 2*j + (r2&1)] = e2hg[idx];
  }
  const float2 emt2 = *(const float2*)&empty_el[2*cp];
  #pragma unroll
  for (int j=0;j<8;j++)
    *(float2*)&stk_s[(8*g+j)*128 + 2*cp] = emt2;
  *(float2*)&halo_top[0][g*128 + 2*cp] = emt2;
  *(float2*)&halo_bot[0][g*128 + 2*cp] = emt2;
  if (tid < 768) whi_s[tid] = Wh2i[tid];
  if (tid < 128){
    hid_pk[CHOFF(tid)] = 0u;
    int cu = tid & 63;
    s_pk[CHOFF(tid)] = packh2(empty_el[2*cu], empty_el[2*cu+1]);
  }
  if (tid < 192){ wbuf[0][tid] = (tid==64)?1.f:0.f; wbuf[1][tid]=0.f; }
  if (tid < 32)  pkwc[tid] = (tid==0)? packh2(1.f,0.f) : 0u;
  __syncthreads();

  int cur = 0;
  for (int t=0;t<T_STEPS;++t){
    // ============ Phase A: ihid (s2h + inp-window) & hid-pre (h2h) ============
    {
      const unsigned* act  = aside ? hid_pk : s_pk;
      const unsigned* actB = act + 48*aks;
      float x0 = 0.f, x1 = 0.f;
      if (aside==0){
        #pragma unroll
        for (int qq=0;qq<4;qq++){
          int r2g = 4*aks + qq;
          unsigned cwE = pkwc[8*aks + 2*qq];
          unsigned cwO = pkwc[8*aks + 2*qq + 1];
          uint4 u = *(const uint4*)&e2h4[r2g*520 + 4*ajp];
          x0 = fdot2(cwE, u.x, x0); x0 = fdot2(cwO, u.y, x0);
          x1 = fdot2(cwE, u.z, x1); x1 = fdot2(cwO, u.w, x1);
        }
      }
      #pragma unroll
      for (int i=0;i<8;i++){
        uint4 A  = *(const uint4*)(actB + 12*(i>>1) + 4*(i&1));
        uint4 Wa = w1r[i], Wb = w1r[8+i];
        x0 = fdot2(A.x,Wa.x,x0); x0 = fdot2(A.y,Wa.y,x0);
        x0 = fdot2(A.z,Wa.z,x0); x0 = fdot2(A.w,Wa.w,x0);
        x1 = fdot2(A.x,Wb.x,x1); x1 = fdot2(A.y,Wb.y,x1);
        x1 = fdot2(A.z,Wb.z,x1); x1 = fdot2(A.w,Wb.w,x1);
      }
      x0 += __shfl_xor(x0,1); x0 += __shfl_xor(x0,2);
      x1 += __shfl_xor(x1,1); x1 += __shfl_xor(x1,2);
      if (aks==0){
        float* dst = aside ? acchp_st : accih_st;
        *(float2*)&dst[STGP(ajp)] = make_float2(x0 + bA0, x1 + bA1);
      }
    }
    __syncthreads();                                   // B1

    // ---- hid finalize + out store (waves 1-2) ----
    if (tid >= 64 && tid < 192){
      int hl = tid - 64;
      int w_ = STGP(hl);
      float2 ih2 = *(const float2*)&accih_st[w_];
      float2 hp2 = *(const float2*)&acchp_st[w_];
      float hn0 = fmaxf(ih2.x+hp2.x, 0.f);
      float hn1 = fmaxf(ih2.y+hp2.y, 0.f);
      hid_pk[CHOFF(hl)] = packh2(hn0,hn1);
      *(float2*)&out[OUT_OFF + t*8192 + b*256 + 2*hl] = make_float2(hn0,hn1);
      if (t==T_STEPS-1) *(float2*)&out[HID_OFF + b*256 + 2*hl] = make_float2(hn0,hn1);
    }

    // ============ Phase B: h2s (inline new hid) & s2u (old tops) ============
    {
      float y0=0.f, y1=0.f;
      #pragma unroll
      for (int i=0;i<4;i++){
        unsigned u0,u1,u2,u3;
        if (h2sSide){
          const int off = 40*ksB + ((i>=2)?20:0) + 8*(i&1);
          float4 a0 = *(const float4*)(accih_st + off);
          float4 a1 = *(const float4*)(accih_st + off + 4);
          float4 c0 = *(const float4*)(acchp_st + off);
          float4 c1 = *(const float4*)(acchp_st + off + 4);
          u0 = packh2(fmaxf(a0.x+c0.x,0.f), fmaxf(a0.y+c0.y,0.f));
          u1 = packh2(fmaxf(a0.z+c0.z,0.f), fmaxf(a0.w+c0.w,0.f));
          u2 = packh2(fmaxf(a1.x+c1.x,0.f), fmaxf(a1.y+c1.y,0.f));
          u3 = packh2(fmaxf(a1.z+c1.z,0.f), fmaxf(a1.w+c1.w,0.f));
        } else {
          uint4 S = *(const uint4*)&s_pk[12*(2*ksB + (i>>1)) + 4*(i&1)];
          u0 = S.x; u1 = S.y; u2 = S.z; u3 = S.w;
        }
        uint4 Wa = wBr[i], Wb = wBr[4+i];
        y0=fdot2(u0,Wa.x,y0); y0=fdot2(u1,Wa.y,y0); y0=fdot2(u2,Wa.z,y0); y0=fdot2(u3,Wa.w,y0);
        y1=fdot2(u0,Wb.x,y1); y1=fdot2(u1,Wb.y,y1); y1=fdot2(u2,Wb.z,y1); y1=fdot2(u3,Wb.w,y1);
      }
      y0 += __shfl_xor(y0,1); y0 += __shfl_xor(y0,2); y0 += __shfl_xor(y0,4);
      y1 += __shfl_xor(y1,1); y1 += __shfl_xor(y1,2); y1 += __shfl_xor(y1,4);
      if (ksB==0){
        float* dst = h2sSide ? pv_s : uv_s;
        dst[2*jpB]   = fmaxf(y0+bB0,0.f);
        dst[2*jpB+1] = fmaxf(y1+bB1,0.f);
      }
    }

    // ---- softmax/gating on wave 0 ----
    if (tid < 64){
      int l = tid;
      float4 av = *(const float4*)&accih_st[20*(l>>2) + 4*(l&3)];
      float4 q0 = *(const float4*)&whi_s[4*l];
      float4 q1 = *(const float4*)&whi_s[256 + 4*l];
      float4 q2 = *(const float4*)&whi_s[512 + 4*l];
      float p0 = av.x*q0.x + av.y*q0.y + av.z*q0.z + av.w*q0.w;
      float p1 = av.x*q1.x + av.y*q1.y + av.z*q1.z + av.w*q1.w;
      float p2 = av.x*q2.x + av.y*q2.y + av.z*q2.z + av.w*q2.w;
      #pragma unroll
      for (int o=1;o<=32;o<<=1){
        p0 += __shfl_xor(p0,o); p1 += __shfl_xor(p1,o); p2 += __shfl_xor(p2,o);
      }
      float i0 = bi0+p0, i1 = bi1+p1, gi = bi2+p2;
      float mx = fmaxf(i0,i1);
      float e0 = expf(i0-mx), e1 = expf(i1-mx);
      float inv = 1.f/(e0+e1);
      float act0 = e0*inv, act1 = e1*inv;
      float gamma = 1.f + log1pf(expf(gi));
      float A0 = powf(act0,gamma), A1 = powf(act1,gamma);
      float sden = A0+A1+1e-16f;
      if (l==0){
        float ppv = A0/sden, pqv = A1/sden;
        pp_s = ppv; pq_s = pqv;
        *(float2*)&out[ACTS_OFF + t*64 + b*2] = make_float2(ppv,pqv);
      }
    }
    __syncthreads();                                   // B3
    const float pp = pp_s, pq = pq_s;

    // ============ Stack update: own rows in stk_s, cross-wave rows via halo ====
    {
      float2 w[10];                                    // rows 8g-1 .. 8g+8
      #pragma unroll
      for (int k=1;k<=8;k++)
        w[k] = *(const float2*)&stk_s[(8*g + k - 1)*128 + 2*cp];
      w[0] = (g>0)  ? *(const float2*)&halo_bot[cur][(g-1)*128 + 2*cp]
                    : make_float2(0.f,0.f);
      w[9] = (g<15) ? *(const float2*)&halo_top[cur][(g+1)*128 + 2*cp]
                    : emt2;
      float2 pv2 = make_float2(0.f,0.f), uv2 = make_float2(0.f,0.f);
      if (g == 0){ pv2 = *(const float2*)&pv_s[2*cp]; uv2 = *(const float2*)&uv_s[2*cp]; }
      float2 nn0, nn1;
      #pragma unroll
      for (int j=0;j<8;j++){
        float2 nv;
        nv.x = pp*w[j].x + pq*w[j+2].x;
        nv.y = pp*w[j].y + pq*w[j+2].y;
        if (j==0 && g==0){
          nv.x = pp*pv2.x + pq*uv2.x;
          nv.y = pp*pv2.y + pq*uv2.y;
        }
        *(float2*)&stk_s[(8*g+j)*128 + 2*cp] = nv;
        if (j==0){ nn0 = nv; *(float2*)&halo_top[cur^1][g*128 + 2*cp] = nv; }
        if (j==1){ nn1 = nv; }
        if (j==7){ *(float2*)&halo_bot[cur^1][g*128 + 2*cp] = nv; }
      }
      if (g == 0){
        *(float2*)&out[TE_OFF + t*4096 + b*128 + 2*cp] = nn0;
        s_pk[CHOFF(cp)]    = packh2(nn0.x, nn0.y);
        s_pk[CHOFF(64+cp)] = packh2(nn1.x, nn1.y);
      }
      // coefficient recurrence for the collapsed buf + next-step packed pairs
      if (tid < 128){
        int k = 64+tid;
        wbuf[cur^1][k] = pp*wbuf[cur][k] + pq*wbuf[cur][k-1];
      } else if (tid < 160){
        int r2 = tid-128;
        int k1 = 65 + t - 2*r2;
        float wa = wbuf[cur][k1], wb2 = wbuf[cur][k1-1], wc2 = wbuf[cur][k1-2];
        pkwc[r2] = packh2(pp*wa+pq*wb2, pp*wb2+pq*wc2);
      }
    }
    __syncthreads();                                   // S_f
    cur ^= 1;
  }

  // ---- final stack output ----
  #pragma unroll
  for (int j=0;j<8;j++)
    *(float2*)&out[STACK_OFF + b*16384 + (8*g+j)*128 + 2*cp] =
      *(const float2*)&stk_s[(8*g+j)*128 + 2*cp];
}

extern "C" void kernel_launch(void* const* d_in, const int* in_sizes, int n_in,
                              void* d_out, int out_size, void* d_ws, size_t ws_size,
                              hipStream_t stream){
  const int*   inputs = (const int*)d_in[0];
  const float* embW   = (const float*)d_in[1];
  const float* We2h   = (const float*)d_in[2];
  const float* b_e2h  = (const float*)d_in[3];
  const float* Ws2h   = (const float*)d_in[4];
  const float* b_s2h  = (const float*)d_in[5];
  const float* Wh2h   = (const float*)d_in[6];
  const float* b_h2h  = (const float*)d_in[7];
  const float* Wh2i   = (const float*)d_in[8];
  const float* b_h2i  = (const float*)d_in[9];
  const float* Wh2s   = (const float*)d_in[10];
  const float* b_h2s  = (const float*)d_in[11];
  const float* Ws2u   = (const float*)d_in[12];
  const float* b_s2u  = (const float*)d_in[13];
  const float* empty  = (const float*)d_in[14];
  unsigned* wsu = (unsigned*)d_ws;

  prep_all<<<dim3(352), dim3(256), 0, stream>>>(inputs, embW, We2h, Ws2h, Wh2h,
                                                Wh2s, Ws2u, (uint4*)wsu,
                                                wsu + E2H_OFF_U);
  srnn_main<<<dim3(32), dim3(1024), 0, stream>>>((const uint4*)wsu, (const unsigned*)wsu,
                                                 b_e2h, b_s2h, b_h2h, Wh2i, b_h2i,
                                                 b_h2s, b_s2u, empty, (float*)d_out);
}